// Round 5
// baseline (1492.935 us; speedup 1.0000x reference)
//
#include <hip/hip_runtime.h>
#include <hip/hip_bf16.h>

// SRPBlock forward — fp16 end-to-end MFMA implicit-GEMM convs + LDS-tiled local attention.
// x=concat(old,new) [4,64,256,256] fp32 NCHW inputs; all activations flow as fp16
// [b][pix][ch] (channel-contiguous); fp32 accumulate everywhere; final out fp32 NCHW.
//
// This revision (tile geometry):
//  * conv_mfma: 16x32 pixel tile (4 waves x 8 rows), round-2's 2-barrier LDS-staged
//    structure otherwise UNCHANGED (rounds 3/4 proved weights must stay LDS-staged
//    and extra occupancy doesn't pay). Per-wave ds_read/MFMA ratio drops 0.5 ->
//    0.375 (LDS read pipe was oversubscribed vs matrix pipe); weight staging and
//    barrier count per pixel halve. LDS 74.25 KB, 2 blocks/CU.
//  * local_sim unchanged from round 2 (verified ~70 us).

#define HH 256
#define WW 256
#define PLANE 65536

typedef _Float16 f16x8 __attribute__((ext_vector_type(8)));
typedef float    f32x4 __attribute__((ext_vector_type(4)));
typedef _Float16 h2    __attribute__((ext_vector_type(2)));

__device__ __forceinline__ unsigned short f2h(float f) {
    _Float16 h = (_Float16)f;                  // v_cvt_f16_f32 (RNE)
    return __builtin_bit_cast(unsigned short, h);
}
__device__ __forceinline__ float h2f(unsigned short u) {
    return (float)__builtin_bit_cast(_Float16, u);
}
__device__ __forceinline__ unsigned pack2h(float a, float b) {
    return (unsigned)f2h(a) | ((unsigned)f2h(b) << 16);
}
__device__ __forceinline__ float dot2h(unsigned a, unsigned b, float c) {
#if __has_builtin(__builtin_amdgcn_fdot2)
    return __builtin_amdgcn_fdot2(__builtin_bit_cast(h2, a),
                                  __builtin_bit_cast(h2, b), c, false);
#else
    h2 av = __builtin_bit_cast(h2, a), bv = __builtin_bit_cast(h2, b);
    return fmaf((float)av.x, (float)bv.x, fmaf((float)av.y, (float)bv.y, c));
#endif
}

// async 16B global -> LDS. LDS dest is wave-uniform base + lane*16 (linear);
// per-lane swizzling must be applied to the GLOBAL source address.
__device__ __forceinline__ void gl16(const unsigned short* g, unsigned short* l) {
    __builtin_amdgcn_global_load_lds(
        (const __attribute__((address_space(1))) unsigned int*)(g),
        (__attribute__((address_space(3))) unsigned int*)(l),
        16, 0, 0);
}

// ---------------- conv3x3 (pad=1, Cout=64) via MFMA 16x16x32 f16 ----------------
// block = 256 thr = 4 waves; tile = 16 cols x 32 rows x 64 outch; wave -> 8 rows.
// K = 9 taps x CIN, chunked by 32 channels; ALL 9 taps' weights staged per chunk
// -> 2 barriers per chunk, 288 MFMAs per wave between barriers.
// Halo = 34 rows x 18 cols = 612 px x 32 ch (38.25 KB) + w 9*64*32 (36 KB)
// = 74.25 KB LDS -> 2 blocks/CU; union'd with the 64 KB epilogue transpose region.
template <int CIN, bool BIAS, bool LEAKY, bool ADDF, bool ADDX, bool MULX, bool OUTF, bool OUTB>
__global__ __launch_bounds__(256, 2) void conv_mfma(
    const unsigned short* __restrict__ in_pc,  // [b][65536][CIN] fp16
    const unsigned short* __restrict__ wb,     // [9][64][CIN] fp16
    const float* __restrict__ bias,
    const unsigned short* __restrict__ addh,   // fp16 [b][pix][64] addend (residual)
    const unsigned short* __restrict__ xh,     // fp16 [b][pix][64] (concat x)
    float* __restrict__ outf,                  // fp32 NCHW
    unsigned short* __restrict__ outb)         // fp16 [b][65536][64]
{
    __shared__ unsigned short smem[38016];     // 74.25 KB
    unsigned short* lds_in = smem;             // 612*32 = 19584 halves
    unsigned short* lds_w  = smem + 19584;     // 9*64*32 = 18432 halves

    const int tid = threadIdx.x;
    const int w   = tid >> 6;
    const int ln  = tid & 63;
    const int m   = ln & 15;    // outch-in-group for A; pixel-col for B/D
    const int q   = ln >> 4;    // quad
    const int b   = blockIdx.z;
    const int tx0 = blockIdx.x * 16, ty0 = blockIdx.y * 32;
    const size_t pixb = (size_t)b * PLANE;
    const bool interior = (blockIdx.x >= 1) && (blockIdx.x <= 14) &&
                          (blockIdx.y >= 1) && (blockIdx.y <= 6);

    f32x4 acc[4][8];
#pragma unroll
    for (int g = 0; g < 4; ++g)
#pragma unroll
        for (int p = 0; p < 8; ++p) acc[g][p] = (f32x4)0.f;

    for (int c2 = 0; c2 < CIN / 32; ++c2) {
        __syncthreads();   // protect previous chunk's reads / epilogue region
        // ---- stage input halo chunk: 612 px (34x18) x 32 ch ----
        if (interior) {
            // unchecked async path: linear LDS dest, swizzled global source
            const unsigned short* inb =
                in_pc + (pixb + (size_t)(ty0 - 1) * 256 + (tx0 - 1)) * CIN + c2 * 32;
#pragma unroll
            for (int it = 0; it < 9; ++it) {
                int u = it * 256 + tid;
                int pix = u >> 2, ps = u & 3;
                int part = ps ^ (pix & 3);
                int hy = pix / 18, hx = pix - hy * 18;
                gl16(inb + ((size_t)hy * 256 + hx) * CIN + part * 8,
                     &lds_in[(it * 256 + (tid & 192)) * 8]);
            }
            if (tid < 144) {   // tail: u = 2304..2447
                int u = 2304 + tid;
                int pix = u >> 2, ps = u & 3;
                int part = ps ^ (pix & 3);
                int hy = pix / 18, hx = pix - hy * 18;
                gl16(inb + ((size_t)hy * 256 + hx) * CIN + part * 8,
                     &lds_in[(2304 + (tid & 192)) * 8]);
            }
        } else {
            // boundary path: checked, zero-filled, via VGPRs
            for (int u = tid; u < 2448; u += 256) {
                int pix = u >> 2, part = u & 3;
                int hy = pix / 18, hx = pix - hy * 18;
                int gy = ty0 + hy - 1, gx = tx0 + hx - 1;
                uint4 val = make_uint4(0u, 0u, 0u, 0u);
                if ((unsigned)gy < 256u && (unsigned)gx < 256u)
                    val = *reinterpret_cast<const uint4*>(
                        in_pc + ((pixb + (size_t)gy * 256 + gx) * CIN + c2 * 32 + part * 8));
                *reinterpret_cast<uint4*>(&lds_in[pix * 32 + ((part ^ (pix & 3)) * 8)]) = val;
            }
        }
        // ---- stage ALL 9 taps' weights for this chunk: 9 x 64 oc x 32 ch (async) ----
        {
            const int oc = tid >> 2, ps = tid & 3;
            const int part = ps ^ (oc & 3);
            const unsigned short* wsrc = wb + (size_t)oc * CIN + c2 * 32 + part * 8;
#pragma unroll
            for (int t = 0; t < 9; ++t)
                gl16(wsrc + (size_t)t * 64 * CIN,
                     &lds_w[t * 2048 + (tid & 192) * 8]);
        }
        __syncthreads();

#pragma unroll
        for (int t = 0; t < 9; ++t) {
            const int dy = t / 3, dx = t - dy * 3;
            f16x8 av[4];
#pragma unroll
            for (int g = 0; g < 4; ++g) {
                int oc = g * 16 + m;
                av[g] = *reinterpret_cast<const f16x8*>(
                    &lds_w[t * 2048 + oc * 32 + ((q ^ (oc & 3)) * 8)]);
            }
#pragma unroll
            for (int p = 0; p < 8; ++p) {
                int hp = (w * 8 + p + dy) * 18 + m + dx;
                f16x8 bv = *reinterpret_cast<const f16x8*>(
                    &lds_in[hp * 32 + ((q ^ (hp & 3)) * 8)]);
#pragma unroll
                for (int g = 0; g < 4; ++g)
                    acc[g][p] = __builtin_amdgcn_mfma_f32_16x16x32_f16(
                        av[g], bv, acc[g][p], 0, 0, 0);
            }
        }
    }

    // ---------------- epilogue ----------------
    // D layout: row(outch-in-grp) = q*4+reg, col(pixel) = m
    const int colx = tx0 + m;
    float4 bvec[4];
    if (BIAS) {
#pragma unroll
        for (int g = 0; g < 4; ++g)
            bvec[g] = *reinterpret_cast<const float4*>(bias + g * 16 + q * 4);
    }
    if (OUTB) __syncthreads();   // protect last tap's LDS reads before overwrite

#pragma unroll
    for (int g = 0; g < 4; ++g) {
#pragma unroll
        for (int p = 0; p < 8; ++p) {
            const int prow = w * 8 + p;
            const int gy   = ty0 + prow;
            const size_t pixg = pixb + (size_t)gy * 256 + colx;
            const int oc0 = g * 16 + q * 4;
            ushort4 a4, x4;
            if (ADDF) a4 = *reinterpret_cast<const ushort4*>(addh + pixg * 64 + oc0);
            if (ADDX || MULX) x4 = *reinterpret_cast<const ushort4*>(xh + pixg * 64 + oc0);
            float vals[4];
#pragma unroll
            for (int r = 0; r < 4; ++r) {
                float v = acc[g][p][r];
                if (BIAS) v += reinterpret_cast<const float*>(&bvec[g])[r];
                if (LEAKY) v = (v >= 0.f) ? v : 0.2f * v;
                if (ADDF) v += h2f(reinterpret_cast<const unsigned short*>(&a4)[r]);
                if (ADDX) v += h2f(reinterpret_cast<const unsigned short*>(&x4)[r]);
                if (MULX) v *= h2f(reinterpret_cast<const unsigned short*>(&x4)[r]);
                if (OUTF)
                    outf[((size_t)(b * 64 + oc0 + r)) * PLANE + (size_t)gy * 256 + colx] = v;
                vals[r] = v;
            }
            if (OUTB) {  // stage to LDS for [pix][64] vector store
                ushort4 pk;
                pk.x = f2h(vals[0]); pk.y = f2h(vals[1]);
                pk.z = f2h(vals[2]); pk.w = f2h(vals[3]);
                int pix   = prow * 16 + m;
                int part8 = g * 4 + q;
                int p16   = (part8 >> 1) ^ (pix & 7);
                *reinterpret_cast<ushort4*>(&smem[pix * 64 + p16 * 8 + (part8 & 1) * 4]) = pk;
            }
        }
    }
    if (OUTB) {
        __syncthreads();
        for (int u = tid; u < 4096; u += 256) {
            int pix = u >> 3, p16 = u & 7;
            uint4 val = *reinterpret_cast<const uint4*>(
                &smem[pix * 64 + ((p16 ^ (pix & 7)) * 8)]);
            int gy = ty0 + (pix >> 4), gx = tx0 + (pix & 15);
            *reinterpret_cast<uint4*>(
                &outb[(pixb + (size_t)gy * 256 + gx) * 64 + p16 * 8]) = val;
        }
    }
}

// ---------------- local similarity (LDS-tiled, fp16 dot2, di-grouped) ----------------
// att[b][pix][p] = dot64(q[pix], k[pix+(di-4,dj-4)]), p=di*9+dj; ch 81..95 = 0.
// Full 64-ch 24x24 K halo staged ONCE (72 KB LDS); g-outer loop keeps only acc[27]
// live (no spills). Channel accumulation order identical to the verified original.
__global__ __launch_bounds__(256)
void local_sim(
    const unsigned short* __restrict__ qh, const unsigned short* __restrict__ kh,
    unsigned short* __restrict__ att)
{
    __shared__ unsigned short lds_k[576 * 64];   // 24*24 px x 64ch fp16 = 73.7 KB

    const int tid = threadIdx.x;
    const int tx = tid & 15, ty = tid >> 4;
    const int bx = blockIdx.x * 16, by = blockIdx.y * 16;
    const int b  = blockIdx.z;
    const size_t pixb = (size_t)b * PLANE;
    const bool interior = (blockIdx.x >= 1) && (blockIdx.x <= 14) &&
                          (blockIdx.y >= 1) && (blockIdx.y <= 14);

    // ---- stage K halo 24x24 x 64ch once; slot = part ^ ((pix ^ pix>>3) & 7) ----
    if (interior) {
        const unsigned short* kb =
            kh + (pixb + (size_t)(by - 4) * 256 + (bx - 4)) * 64;
#pragma unroll
        for (int it = 0; it < 18; ++it) {
            int u = it * 256 + tid;
            int pix = u >> 3, sl = u & 7;
            int part = sl ^ ((pix ^ (pix >> 3)) & 7);
            int hy = pix / 24, hx = pix - hy * 24;
            gl16(kb + ((size_t)hy * 256 + hx) * 64 + part * 8,
                 &lds_k[(it * 256 + (tid & 192)) * 8]);
        }
    } else {
        for (int u = tid; u < 4608; u += 256) {
            int pix = u >> 3, part = u & 7;
            int hy = pix / 24, hx = pix - hy * 24;
            int gy = by + hy - 4, gx = bx + hx - 4;
            uint4 val = make_uint4(0u, 0u, 0u, 0u);
            if ((unsigned)gy < 256u && (unsigned)gx < 256u)
                val = *reinterpret_cast<const uint4*>(
                    kh + ((pixb + (size_t)gy * 256 + gx) * 64 + part * 8));
            int sl = part ^ ((pix ^ (pix >> 3)) & 7);
            *reinterpret_cast<uint4*>(&lds_k[pix * 64 + sl * 8]) = val;
        }
    }
    __syncthreads();

    const unsigned short* qbase = qh + (pixb + (size_t)(by + ty) * 256 + bx + tx) * 64;
    unsigned short* op = att + (pixb + (size_t)(by + ty) * 256 + bx + tx) * 96;

    uint4 qv[8];
#pragma unroll
    for (int j = 0; j < 8; ++j)
        qv[j] = *reinterpret_cast<const uint4*>(qbase + j * 8);

#pragma unroll
    for (int g = 0; g < 3; ++g) {
        float acc[27];
#pragma unroll
        for (int i = 0; i < 27; ++i) acc[i] = 0.f;

#pragma unroll
        for (int dil = 0; dil < 3; ++dil) {
            const int hrow = (ty + g * 3 + dil) * 24 + tx;
#pragma unroll
            for (int dj = 0; dj < 9; ++dj) {
                const int hp = hrow + dj;
                const int gs = (hp ^ (hp >> 3)) & 7;
                float s = acc[dil * 9 + dj];
#pragma unroll
                for (int part = 0; part < 8; ++part) {
                    const uint4 kv = *reinterpret_cast<const uint4*>(
                        &lds_k[hp * 64 + ((part ^ gs) * 8)]);
                    s = dot2h(qv[part].x, kv.x, s);
                    s = dot2h(qv[part].y, kv.y, s);
                    s = dot2h(qv[part].z, kv.z, s);
                    s = dot2h(qv[part].w, kv.w, s);
                }
                acc[dil * 9 + dj] = s;
            }
        }

        // ---- store this group's 27 fp16 values at op + g*27 ----
        unsigned short* o = op + g * 27;
        if (g == 0) {
            uint4 A = {pack2h(acc[0], acc[1]),  pack2h(acc[2], acc[3]),
                       pack2h(acc[4], acc[5]),  pack2h(acc[6], acc[7])};
            uint4 B = {pack2h(acc[8], acc[9]),  pack2h(acc[10], acc[11]),
                       pack2h(acc[12], acc[13]), pack2h(acc[14], acc[15])};
            uint2 C = {pack2h(acc[16], acc[17]), pack2h(acc[18], acc[19])};
            uint2 D = {pack2h(acc[20], acc[21]), pack2h(acc[22], acc[23])};
            *reinterpret_cast<uint4*>(o)      = A;
            *reinterpret_cast<uint4*>(o + 8)  = B;
            *reinterpret_cast<uint2*>(o + 16) = C;
            *reinterpret_cast<uint2*>(o + 20) = D;
            *reinterpret_cast<unsigned*>(o + 24) = pack2h(acc[24], acc[25]);
            o[26] = f2h(acc[26]);
        } else if (g == 1) {
            o[0] = f2h(acc[0]);
            *reinterpret_cast<unsigned*>(o + 1) = pack2h(acc[1], acc[2]);
            *reinterpret_cast<unsigned*>(o + 3) = pack2h(acc[3], acc[4]);
            uint4 A = {pack2h(acc[5], acc[6]),   pack2h(acc[7], acc[8]),
                       pack2h(acc[9], acc[10]),  pack2h(acc[11], acc[12])};
            uint4 B = {pack2h(acc[13], acc[14]), pack2h(acc[15], acc[16]),
                       pack2h(acc[17], acc[18]), pack2h(acc[19], acc[20])};
            *reinterpret_cast<uint4*>(o + 5)  = A;
            *reinterpret_cast<uint4*>(o + 13) = B;
            uint2 C = {pack2h(acc[21], acc[22]), pack2h(acc[23], acc[24])};
            *reinterpret_cast<uint2*>(o + 21) = C;
            *reinterpret_cast<unsigned*>(o + 25) = pack2h(acc[25], acc[26]);
        } else {
            *reinterpret_cast<unsigned*>(o) = pack2h(acc[0], acc[1]);
            uint4 A = {pack2h(acc[2], acc[3]),   pack2h(acc[4], acc[5]),
                       pack2h(acc[6], acc[7]),   pack2h(acc[8], acc[9])};
            uint4 B = {pack2h(acc[10], acc[11]), pack2h(acc[12], acc[13]),
                       pack2h(acc[14], acc[15]), pack2h(acc[16], acc[17])};
            *reinterpret_cast<uint4*>(o + 2)  = A;
            *reinterpret_cast<uint4*>(o + 10) = B;
            uint2 C = {pack2h(acc[18], acc[19]), pack2h(acc[20], acc[21])};
            *reinterpret_cast<uint2*>(o + 18) = C;
            *reinterpret_cast<unsigned*>(o + 22) = pack2h(acc[22], acc[23]);
            *reinterpret_cast<unsigned*>(o + 24) = pack2h(acc[24], acc[25]);
            o[26] = f2h(acc[26]);
        }
    }

    // zero channels 81..95
    op[81] = 0;
    *reinterpret_cast<unsigned*>(op + 82) = 0u;
    uint2 z2 = {0u, 0u};
    uint4 z4 = {0u, 0u, 0u, 0u};
    *reinterpret_cast<uint2*>(op + 84) = z2;
    *reinterpret_cast<uint4*>(op + 88) = z4;
}

// ---------------- pack x: fp32 NCHW old/new -> fp16 [b][pix][64] ----------------
__global__ __launch_bounds__(256) void pack_x(
    const float* __restrict__ old_, const float* __restrict__ new_,
    unsigned short* __restrict__ xb)
{
    __shared__ unsigned short lds[256 * 64];
    const int tid = threadIdx.x;
    const int b = blockIdx.y;
    const size_t pixbase = (size_t)blockIdx.x * 256;
#pragma unroll
    for (int cg = 0; cg < 8; ++cg) {
        unsigned pk[4];
#pragma unroll
        for (int h = 0; h < 4; ++h) {
            int c0 = cg * 8 + h * 2;
            const float* s0 = (c0 < 32) ? old_ : new_;
            const float* s1 = ((c0 + 1) < 32) ? old_ : new_;
            float f0 = s0[((size_t)b * 32 + (c0 & 31)) * PLANE + pixbase + tid];
            float f1 = s1[((size_t)b * 32 + ((c0 + 1) & 31)) * PLANE + pixbase + tid];
            pk[h] = pack2h(f0, f1);
        }
        int p16 = cg ^ (tid & 7);
        uint4 v; v.x = pk[0]; v.y = pk[1]; v.z = pk[2]; v.w = pk[3];
        *reinterpret_cast<uint4*>(&lds[tid * 64 + p16 * 8]) = v;
    }
    __syncthreads();
    for (int r = 0; r < 8; ++r) {
        int u = r * 256 + tid;
        int pix = u >> 3, p16 = u & 7;
        uint4 v = *reinterpret_cast<const uint4*>(&lds[pix * 64 + ((p16 ^ (pix & 7)) * 8)]);
        *reinterpret_cast<uint4*>(
            &xb[((size_t)b * PLANE + pixbase + pix) * 64 + p16 * 8]) = v;
    }
}

// ---------------- weight prep: fp32 OIHW -> fp16 [9][64][CIN] ----------------
__global__ void prep_wstd(const float* __restrict__ wq, const float* __restrict__ wk,
                          const float* __restrict__ wo1, const float* __restrict__ wo2,
                          const float* __restrict__ rw1, const float* __restrict__ rw2,
                          unsigned short* __restrict__ wstd)
{
    const int c = blockIdx.y;  // 0..19
    const float* src;
    if (c == 0) src = wq;
    else if (c == 1) src = wk;
    else if (c == 2) src = wo1;
    else if (c == 3) src = wo2;
    else if (c < 12) src = rw1 + (size_t)(c - 4) * 36864;
    else src = rw2 + (size_t)(c - 12) * 36864;
    int idx = blockIdx.x * 256 + threadIdx.x;  // 0..4095
    int o = idx >> 6, i = idx & 63;
    const float* s = src + (size_t)(o * 64 + i) * 9;
    unsigned short* d = wstd + (size_t)c * 36864 + (size_t)o * 64 + i;
#pragma unroll
    for (int t = 0; t < 9; ++t) d[(size_t)t * 4096] = f2h(s[t]);
}

__global__ void prep_wv(const float* __restrict__ wv, unsigned short* __restrict__ wv96)
{
    int idx = blockIdx.x * 256 + threadIdx.x;  // < 6144
    int o = idx / 96, i = idx - o * 96;
    unsigned short* d = wv96 + (size_t)o * 96 + i;
    if (i < 81) {
        const float* s = wv + (size_t)(o * 81 + i) * 9;
#pragma unroll
        for (int t = 0; t < 9; ++t) d[(size_t)t * 6144] = f2h(s[t]);
    } else {
#pragma unroll
        for (int t = 0; t < 9; ++t) d[(size_t)t * 6144] = 0;
    }
}

extern "C" void kernel_launch(void* const* d_in, const int* in_sizes, int n_in,
                              void* d_out, int out_size, void* d_ws, size_t ws_size,
                              hipStream_t stream)
{
    const float* old_ = (const float*)d_in[0];
    const float* new_ = (const float*)d_in[1];
    const float* wq  = (const float*)d_in[2];  const float* bq  = (const float*)d_in[3];
    const float* wk  = (const float*)d_in[4];  const float* bk  = (const float*)d_in[5];
    const float* wv  = (const float*)d_in[6];  const float* bv  = (const float*)d_in[7];
    const float* wo1 = (const float*)d_in[8];  const float* bo1 = (const float*)d_in[9];
    const float* rw1 = (const float*)d_in[10]; const float* rw2 = (const float*)d_in[11];
    const float* wo2 = (const float*)d_in[12]; const float* bo2 = (const float*)d_in[13];
    float* out = (float*)d_out;

    char* ws = (char*)d_ws;
    // X : xh fp16 (32 MiB, persistent)
    // P1: q -> y_a (32 MiB) ; P2: k -> xv -> h1 (32 MiB) ; P3: att96(48) -> y_b
    unsigned short* X   = (unsigned short*)(ws);
    unsigned short* P1  = (unsigned short*)(ws + 33554432ull);
    unsigned short* P2  = (unsigned short*)(ws + 67108864ull);
    unsigned short* P3  = (unsigned short*)(ws + 100663296ull);
    unsigned short* wst = (unsigned short*)(ws + 150994944ull);   // 20*36864 fp16
    unsigned short* wv96= (unsigned short*)(ws + 152469504ull);   // 9*64*96 fp16

    const dim3 cgrid(16, 8, 4), cblk(256);     // conv: 16x32 pixel tiles
    const dim3 sgrid(16, 16, 4);               // local_sim: 16x16 tiles

    prep_wstd<<<dim3(16, 20), 256, 0, stream>>>(wq, wk, wo1, wo2, rw1, rw2, wst);
    prep_wv<<<dim3(24), 256, 0, stream>>>(wv, wv96);
    pack_x<<<dim3(256, 4), 256, 0, stream>>>(old_, new_, X);

    // q = conv(x, wq, bq); k = conv(x, wk, bk)
    conv_mfma<64, true, false, false, false, false, false, true>
        <<<cgrid, cblk, 0, stream>>>(X, wst + 0ull * 36864, bq, nullptr, nullptr, nullptr, P1);
    conv_mfma<64, true, false, false, false, false, false, true>
        <<<cgrid, cblk, 0, stream>>>(X, wst + 1ull * 36864, bk, nullptr, nullptr, nullptr, P2);
    // att (fp16, 96ch padded)
    local_sim<<<sgrid, cblk, 0, stream>>>(P1, P2, P3);
    // xv = x * (conv(att, wv) + bv)   [MULX fused]
    conv_mfma<96, true, false, false, false, true, false, true>
        <<<cgrid, cblk, 0, stream>>>(P3, wv96, bv, nullptr, X, nullptr, P2);
    // y0 = conv(xv, wo1, bo1) -> P1
    conv_mfma<64, true, false, false, false, false, false, true>
        <<<cgrid, cblk, 0, stream>>>(P2, wst + 2ull * 36864, bo1, nullptr, nullptr, nullptr, P1);
    // 8 ResBlocks; y ping-pong P1 <-> P3, h1 in P2; residual add fused in conv2
    for (int i = 0; i < 8; ++i) {
        unsigned short* ysrc = (i & 1) ? P3 : P1;
        unsigned short* ydst = (i & 1) ? P1 : P3;
        conv_mfma<64, false, true, false, false, false, false, true>
            <<<cgrid, cblk, 0, stream>>>(ysrc, wst + (size_t)(4 + i) * 36864, nullptr,
                                         nullptr, nullptr, nullptr, P2);
        conv_mfma<64, false, false, true, false, false, false, true>
            <<<cgrid, cblk, 0, stream>>>(P2, wst + (size_t)(12 + i) * 36864, nullptr,
                                         ysrc, nullptr, nullptr, ydst);
    }
    // out = conv(y, wo2, bo2) + x   [ADDX fused]; final y in P1
    conv_mfma<64, true, false, false, true, false, true, false>
        <<<cgrid, cblk, 0, stream>>>(P1, wst + 3ull * 36864, bo2, nullptr, X, out, nullptr);
}

// Round 6
// 892.429 us; speedup vs baseline: 1.6729x; 1.6729x over previous
//
#include <hip/hip_runtime.h>
#include <hip/hip_bf16.h>

// SRPBlock forward — fp16 end-to-end MFMA implicit-GEMM convs + LDS-tiled local attention.
// x=concat(old,new) [4,64,256,256] fp32 NCHW inputs; all activations flow as fp16
// [b][pix][ch] (channel-contiguous); fp32 accumulate everywhere; final out fp32 NCHW.
//
// This revision:
//  * conv_mfma: EXACT revert to the round-2 kernel and grid (16,16,4) — the 878 us
//    anchor. (R3/R4/R5 conv bets all regressed; R5 also showed the grid/XCD mapping
//    is part of the tuned state.)
//  * local_sim: 2 horizontally-adjacent pixels per thread (128-thread blocks, same
//    16x16 tile, same 72 KB halo, same swizzle/grid). The shared 10-column K-window
//    union cuts LDS-read volume ~44% (local_sim was LDS-read-BW-bound: 648 b128
//    reads/thread ~= 52 of its 70 us). Accumulation order preserved per output.

#define HH 256
#define WW 256
#define PLANE 65536

typedef _Float16 f16x8 __attribute__((ext_vector_type(8)));
typedef float    f32x4 __attribute__((ext_vector_type(4)));
typedef _Float16 h2    __attribute__((ext_vector_type(2)));

__device__ __forceinline__ unsigned short f2h(float f) {
    _Float16 h = (_Float16)f;                  // v_cvt_f16_f32 (RNE)
    return __builtin_bit_cast(unsigned short, h);
}
__device__ __forceinline__ float h2f(unsigned short u) {
    return (float)__builtin_bit_cast(_Float16, u);
}
__device__ __forceinline__ unsigned pack2h(float a, float b) {
    return (unsigned)f2h(a) | ((unsigned)f2h(b) << 16);
}
__device__ __forceinline__ float dot2h(unsigned a, unsigned b, float c) {
#if __has_builtin(__builtin_amdgcn_fdot2)
    return __builtin_amdgcn_fdot2(__builtin_bit_cast(h2, a),
                                  __builtin_bit_cast(h2, b), c, false);
#else
    h2 av = __builtin_bit_cast(h2, a), bv = __builtin_bit_cast(h2, b);
    return fmaf((float)av.x, (float)bv.x, fmaf((float)av.y, (float)bv.y, c));
#endif
}

// async 16B global -> LDS. LDS dest is wave-uniform base + lane*16 (linear);
// per-lane swizzling must be applied to the GLOBAL source address.
__device__ __forceinline__ void gl16(const unsigned short* g, unsigned short* l) {
    __builtin_amdgcn_global_load_lds(
        (const __attribute__((address_space(1))) unsigned int*)(g),
        (__attribute__((address_space(3))) unsigned int*)(l),
        16, 0, 0);
}

// ---------------- conv3x3 (pad=1, Cout=64) via MFMA 16x16x32 f16 ----------------
// block = 256 thr = 4 waves; tile = 16x16 pixels x 64 outch.
// K = 9 taps x CIN, chunked by 32 channels; ALL 9 taps' weights staged per chunk
// -> only 2 barriers per chunk, 144 straight-line MFMAs between barriers.
// LDS: in 324px*32ch (20.25KB) + w 9*64*32 (36KB) = 57.6KB, union'd with the
// 32KB epilogue transpose region.
template <int CIN, bool BIAS, bool LEAKY, bool ADDF, bool ADDX, bool MULX, bool OUTF, bool OUTB>
__global__ __launch_bounds__(256, 2) void conv_mfma(
    const unsigned short* __restrict__ in_pc,  // [b][65536][CIN] fp16
    const unsigned short* __restrict__ wb,     // [9][64][CIN] fp16
    const float* __restrict__ bias,
    const unsigned short* __restrict__ addh,   // fp16 [b][pix][64] addend (residual)
    const unsigned short* __restrict__ xh,     // fp16 [b][pix][64] (concat x)
    float* __restrict__ outf,                  // fp32 NCHW
    unsigned short* __restrict__ outb)         // fp16 [b][65536][64]
{
    __shared__ unsigned short smem[28800];     // 57.6 KB
    unsigned short* lds_in = smem;             // 324*32 = 10368 halves
    unsigned short* lds_w  = smem + 10368;     // 9*64*32 = 18432 halves

    const int tid = threadIdx.x;
    const int w   = tid >> 6;
    const int ln  = tid & 63;
    const int m   = ln & 15;    // outch-in-group for A; pixel-col for B/D
    const int q   = ln >> 4;    // quad
    const int b   = blockIdx.z;
    const int tx0 = blockIdx.x * 16, ty0 = blockIdx.y * 16;
    const size_t pixb = (size_t)b * PLANE;
    const bool interior = (blockIdx.x >= 1) && (blockIdx.x <= 14) &&
                          (blockIdx.y >= 1) && (blockIdx.y <= 14);

    f32x4 acc[4][4];
#pragma unroll
    for (int g = 0; g < 4; ++g)
#pragma unroll
        for (int p = 0; p < 4; ++p) acc[g][p] = (f32x4)0.f;

    for (int c2 = 0; c2 < CIN / 32; ++c2) {
        __syncthreads();   // protect previous chunk's reads / epilogue region
        // ---- stage input halo chunk: 324 px x 32 ch ----
        if (interior) {
            // unchecked async path: linear LDS dest, swizzled global source
            const unsigned short* inb =
                in_pc + (pixb + (size_t)(ty0 - 1) * 256 + (tx0 - 1)) * CIN + c2 * 32;
#pragma unroll
            for (int it = 0; it < 5; ++it) {
                int u = it * 256 + tid;
                int pix = u >> 2, ps = u & 3;
                int part = ps ^ (pix & 3);
                int hy = pix / 18, hx = pix - hy * 18;
                gl16(inb + ((size_t)hy * 256 + hx) * CIN + part * 8,
                     &lds_in[(it * 256 + (tid & 192)) * 8]);
            }
            if (tid < 16) {   // tail: u = 1280..1295 (wave 0, lanes 0..15)
                int u = 1280 + tid;
                int pix = u >> 2, ps = u & 3;
                int part = ps ^ (pix & 3);
                int hy = pix / 18, hx = pix - hy * 18;
                gl16(inb + ((size_t)hy * 256 + hx) * CIN + part * 8,
                     &lds_in[1280 * 8]);
            }
        } else {
            // boundary path: checked, zero-filled, via VGPRs
            for (int u = tid; u < 1296; u += 256) {
                int pix = u >> 2, part = u & 3;
                int hy = pix / 18, hx = pix - hy * 18;
                int gy = ty0 + hy - 1, gx = tx0 + hx - 1;
                uint4 val = make_uint4(0u, 0u, 0u, 0u);
                if ((unsigned)gy < 256u && (unsigned)gx < 256u)
                    val = *reinterpret_cast<const uint4*>(
                        in_pc + ((pixb + (size_t)gy * 256 + gx) * CIN + c2 * 32 + part * 8));
                *reinterpret_cast<uint4*>(&lds_in[pix * 32 + ((part ^ (pix & 3)) * 8)]) = val;
            }
        }
        // ---- stage ALL 9 taps' weights for this chunk: 9 x 64 oc x 32 ch (async) ----
        {
            const int oc = tid >> 2, ps = tid & 3;
            const int part = ps ^ (oc & 3);
            const unsigned short* wsrc = wb + (size_t)oc * CIN + c2 * 32 + part * 8;
#pragma unroll
            for (int t = 0; t < 9; ++t)
                gl16(wsrc + (size_t)t * 64 * CIN,
                     &lds_w[t * 2048 + (tid & 192) * 8]);
        }
        __syncthreads();

#pragma unroll
        for (int t = 0; t < 9; ++t) {
            const int dy = t / 3, dx = t - dy * 3;
            f16x8 av[4], bv[4];
#pragma unroll
            for (int g = 0; g < 4; ++g) {
                int oc = g * 16 + m;
                av[g] = *reinterpret_cast<const f16x8*>(
                    &lds_w[t * 2048 + oc * 32 + ((q ^ (oc & 3)) * 8)]);
            }
#pragma unroll
            for (int p = 0; p < 4; ++p) {
                int hp = (w * 4 + p + dy) * 18 + m + dx;
                bv[p] = *reinterpret_cast<const f16x8*>(
                    &lds_in[hp * 32 + ((q ^ (hp & 3)) * 8)]);
            }
#pragma unroll
            for (int g = 0; g < 4; ++g)
#pragma unroll
                for (int p = 0; p < 4; ++p)
                    acc[g][p] = __builtin_amdgcn_mfma_f32_16x16x32_f16(
                        av[g], bv[p], acc[g][p], 0, 0, 0);
        }
    }

    // ---------------- epilogue ----------------
    // D layout: row(outch-in-grp) = q*4+reg, col(pixel) = m
    const int colx = tx0 + m;
    float4 bvec[4];
    if (BIAS) {
#pragma unroll
        for (int g = 0; g < 4; ++g)
            bvec[g] = *reinterpret_cast<const float4*>(bias + g * 16 + q * 4);
    }
    if (OUTB) __syncthreads();   // protect last tap's LDS reads before overwrite

#pragma unroll
    for (int g = 0; g < 4; ++g) {
#pragma unroll
        for (int p = 0; p < 4; ++p) {
            const int prow = w * 4 + p;
            const int gy   = ty0 + prow;
            const size_t pixg = pixb + (size_t)gy * 256 + colx;
            const int oc0 = g * 16 + q * 4;
            ushort4 a4, x4;
            if (ADDF) a4 = *reinterpret_cast<const ushort4*>(addh + pixg * 64 + oc0);
            if (ADDX || MULX) x4 = *reinterpret_cast<const ushort4*>(xh + pixg * 64 + oc0);
            float vals[4];
#pragma unroll
            for (int r = 0; r < 4; ++r) {
                float v = acc[g][p][r];
                if (BIAS) v += reinterpret_cast<const float*>(&bvec[g])[r];
                if (LEAKY) v = (v >= 0.f) ? v : 0.2f * v;
                if (ADDF) v += h2f(reinterpret_cast<const unsigned short*>(&a4)[r]);
                if (ADDX) v += h2f(reinterpret_cast<const unsigned short*>(&x4)[r]);
                if (MULX) v *= h2f(reinterpret_cast<const unsigned short*>(&x4)[r]);
                if (OUTF)
                    outf[((size_t)(b * 64 + oc0 + r)) * PLANE + (size_t)gy * 256 + colx] = v;
                vals[r] = v;
            }
            if (OUTB) {  // stage to LDS for [pix][64] vector store
                ushort4 pk;
                pk.x = f2h(vals[0]); pk.y = f2h(vals[1]);
                pk.z = f2h(vals[2]); pk.w = f2h(vals[3]);
                int pix   = prow * 16 + m;
                int part8 = g * 4 + q;
                int p16   = (part8 >> 1) ^ (pix & 7);
                *reinterpret_cast<ushort4*>(&smem[pix * 64 + p16 * 8 + (part8 & 1) * 4]) = pk;
            }
        }
    }
    if (OUTB) {
        __syncthreads();
        for (int u = tid; u < 2048; u += 256) {
            int pix = u >> 3, p16 = u & 7;
            uint4 val = *reinterpret_cast<const uint4*>(
                &smem[pix * 64 + ((p16 ^ (pix & 7)) * 8)]);
            int gy = ty0 + (pix >> 4), gx = tx0 + (pix & 15);
            *reinterpret_cast<uint4*>(
                &outb[(pixb + (size_t)gy * 256 + gx) * 64 + p16 * 8]) = val;
        }
    }
}

// ---------------- local similarity (LDS-tiled, fp16 dot2, 2 px/thread) ----------------
// att[b][pix][p] = dot64(q[pix], k[pix+(di-4,dj-4)]), p=di*9+dj; ch 81..95 = 0.
// 128-thread blocks; thread (ty, txp) owns pixels (ty, 2*txp) and (ty, 2*txp+1).
// Their K-windows share 8 of 9 columns -> the 10-column union is read once and
// feeds both accumulators (LDS-read volume -44%; kernel was LDS-BW-bound).
// Full 64-ch 24x24 K halo staged ONCE (72 KB LDS), same swizzle/grid as round 2.

#define STORE27(acc, optr) do {                                                   \
    unsigned short* o = (optr);                                                   \
    if (g == 0) {                                                                 \
        uint4 A = {pack2h(acc[0], acc[1]),  pack2h(acc[2], acc[3]),               \
                   pack2h(acc[4], acc[5]),  pack2h(acc[6], acc[7])};              \
        uint4 B = {pack2h(acc[8], acc[9]),  pack2h(acc[10], acc[11]),             \
                   pack2h(acc[12], acc[13]), pack2h(acc[14], acc[15])};           \
        uint2 C = {pack2h(acc[16], acc[17]), pack2h(acc[18], acc[19])};           \
        uint2 D = {pack2h(acc[20], acc[21]), pack2h(acc[22], acc[23])};           \
        *reinterpret_cast<uint4*>(o)      = A;                                    \
        *reinterpret_cast<uint4*>(o + 8)  = B;                                    \
        *reinterpret_cast<uint2*>(o + 16) = C;                                    \
        *reinterpret_cast<uint2*>(o + 20) = D;                                    \
        *reinterpret_cast<unsigned*>(o + 24) = pack2h(acc[24], acc[25]);          \
        o[26] = f2h(acc[26]);                                                     \
    } else if (g == 1) {                                                          \
        o[0] = f2h(acc[0]);                                                       \
        *reinterpret_cast<unsigned*>(o + 1) = pack2h(acc[1], acc[2]);             \
        *reinterpret_cast<unsigned*>(o + 3) = pack2h(acc[3], acc[4]);             \
        uint4 A = {pack2h(acc[5], acc[6]),   pack2h(acc[7], acc[8]),              \
                   pack2h(acc[9], acc[10]),  pack2h(acc[11], acc[12])};           \
        uint4 B = {pack2h(acc[13], acc[14]), pack2h(acc[15], acc[16]),            \
                   pack2h(acc[17], acc[18]), pack2h(acc[19], acc[20])};           \
        *reinterpret_cast<uint4*>(o + 5)  = A;                                    \
        *reinterpret_cast<uint4*>(o + 13) = B;                                    \
        uint2 C = {pack2h(acc[21], acc[22]), pack2h(acc[23], acc[24])};           \
        *reinterpret_cast<uint2*>(o + 21) = C;                                    \
        *reinterpret_cast<unsigned*>(o + 25) = pack2h(acc[25], acc[26]);          \
    } else {                                                                      \
        *reinterpret_cast<unsigned*>(o) = pack2h(acc[0], acc[1]);                 \
        uint4 A = {pack2h(acc[2], acc[3]),   pack2h(acc[4], acc[5]),              \
                   pack2h(acc[6], acc[7]),   pack2h(acc[8], acc[9])};             \
        uint4 B = {pack2h(acc[10], acc[11]), pack2h(acc[12], acc[13]),            \
                   pack2h(acc[14], acc[15]), pack2h(acc[16], acc[17])};           \
        *reinterpret_cast<uint4*>(o + 2)  = A;                                    \
        *reinterpret_cast<uint4*>(o + 10) = B;                                    \
        uint2 C = {pack2h(acc[18], acc[19]), pack2h(acc[20], acc[21])};           \
        *reinterpret_cast<uint2*>(o + 18) = C;                                    \
        *reinterpret_cast<unsigned*>(o + 22) = pack2h(acc[22], acc[23]);          \
        *reinterpret_cast<unsigned*>(o + 24) = pack2h(acc[24], acc[25]);          \
        o[26] = f2h(acc[26]);                                                     \
    }                                                                             \
} while (0)

__global__ __launch_bounds__(128)
void local_sim(
    const unsigned short* __restrict__ qh, const unsigned short* __restrict__ kh,
    unsigned short* __restrict__ att)
{
    __shared__ unsigned short lds_k[576 * 64];   // 24*24 px x 64ch fp16 = 73.7 KB

    const int tid = threadIdx.x;                 // 0..127
    const int txp = tid & 7;                     // pixel-pair column
    const int ty  = tid >> 3;                    // 0..15
    const int bx = blockIdx.x * 16, by = blockIdx.y * 16;
    const int b  = blockIdx.z;
    const size_t pixb = (size_t)b * PLANE;
    const bool interior = (blockIdx.x >= 1) && (blockIdx.x <= 14) &&
                          (blockIdx.y >= 1) && (blockIdx.y <= 14);

    // ---- stage K halo 24x24 x 64ch once; slot = part ^ ((pix ^ pix>>3) & 7) ----
    if (interior) {
        const unsigned short* kb =
            kh + (pixb + (size_t)(by - 4) * 256 + (bx - 4)) * 64;
#pragma unroll
        for (int it = 0; it < 36; ++it) {
            int u = it * 128 + tid;
            int pix = u >> 3, sl = u & 7;
            int part = sl ^ ((pix ^ (pix >> 3)) & 7);
            int hy = pix / 24, hx = pix - hy * 24;
            gl16(kb + ((size_t)hy * 256 + hx) * 64 + part * 8,
                 &lds_k[(it * 128 + (tid & 64)) * 8]);
        }
    } else {
        for (int u = tid; u < 4608; u += 128) {
            int pix = u >> 3, part = u & 7;
            int hy = pix / 24, hx = pix - hy * 24;
            int gy = by + hy - 4, gx = bx + hx - 4;
            uint4 val = make_uint4(0u, 0u, 0u, 0u);
            if ((unsigned)gy < 256u && (unsigned)gx < 256u)
                val = *reinterpret_cast<const uint4*>(
                    kh + ((pixb + (size_t)gy * 256 + gx) * 64 + part * 8));
            int sl = part ^ ((pix ^ (pix >> 3)) & 7);
            *reinterpret_cast<uint4*>(&lds_k[pix * 64 + sl * 8]) = val;
        }
    }
    __syncthreads();

    const int px0 = bx + 2 * txp;
    const unsigned short* qb = qh + (pixb + (size_t)(by + ty) * 256 + px0) * 64;
    unsigned short* op0 = att + (pixb + (size_t)(by + ty) * 256 + px0) * 96;
    unsigned short* op1 = op0 + 96;

    uint4 qv0[8], qv1[8];
#pragma unroll
    for (int j = 0; j < 8; ++j) {
        qv0[j] = *reinterpret_cast<const uint4*>(qb + j * 8);
        qv1[j] = *reinterpret_cast<const uint4*>(qb + 64 + j * 8);
    }

#pragma unroll
    for (int g = 0; g < 3; ++g) {
        float a0[27], a1[27];
#pragma unroll
        for (int i = 0; i < 27; ++i) { a0[i] = 0.f; a1[i] = 0.f; }

#pragma unroll
        for (int dil = 0; dil < 3; ++dil) {
            const int hrow = (ty + g * 3 + dil) * 24 + 2 * txp;
#pragma unroll
            for (int dj = 0; dj < 10; ++dj) {     // union of both pixels' windows
                const int hp = hrow + dj;
                const int gs = (hp ^ (hp >> 3)) & 7;
                float s0 = 0.f, s1 = 0.f;
                if (dj < 9)  s0 = a0[dil * 9 + dj];
                if (dj >= 1) s1 = a1[dil * 9 + dj - 1];
#pragma unroll
                for (int part = 0; part < 8; ++part) {
                    const uint4 kv = *reinterpret_cast<const uint4*>(
                        &lds_k[hp * 64 + ((part ^ gs) * 8)]);
                    if (dj < 9) {
                        s0 = dot2h(qv0[part].x, kv.x, s0);
                        s0 = dot2h(qv0[part].y, kv.y, s0);
                        s0 = dot2h(qv0[part].z, kv.z, s0);
                        s0 = dot2h(qv0[part].w, kv.w, s0);
                    }
                    if (dj >= 1) {
                        s1 = dot2h(qv1[part].x, kv.x, s1);
                        s1 = dot2h(qv1[part].y, kv.y, s1);
                        s1 = dot2h(qv1[part].z, kv.z, s1);
                        s1 = dot2h(qv1[part].w, kv.w, s1);
                    }
                }
                if (dj < 9)  a0[dil * 9 + dj]     = s0;
                if (dj >= 1) a1[dil * 9 + dj - 1] = s1;
            }
        }

        STORE27(a0, op0 + g * 27);
        STORE27(a1, op1 + g * 27);
    }

    // zero channels 81..95 for both pixels
    {
        uint2 z2 = {0u, 0u};
        uint4 z4 = {0u, 0u, 0u, 0u};
        op0[81] = 0;
        *reinterpret_cast<unsigned*>(op0 + 82) = 0u;
        *reinterpret_cast<uint2*>(op0 + 84) = z2;
        *reinterpret_cast<uint4*>(op0 + 88) = z4;
        op1[81] = 0;
        *reinterpret_cast<unsigned*>(op1 + 82) = 0u;
        *reinterpret_cast<uint2*>(op1 + 84) = z2;
        *reinterpret_cast<uint4*>(op1 + 88) = z4;
    }
}

// ---------------- pack x: fp32 NCHW old/new -> fp16 [b][pix][64] ----------------
__global__ __launch_bounds__(256) void pack_x(
    const float* __restrict__ old_, const float* __restrict__ new_,
    unsigned short* __restrict__ xb)
{
    __shared__ unsigned short lds[256 * 64];
    const int tid = threadIdx.x;
    const int b = blockIdx.y;
    const size_t pixbase = (size_t)blockIdx.x * 256;
#pragma unroll
    for (int cg = 0; cg < 8; ++cg) {
        unsigned pk[4];
#pragma unroll
        for (int h = 0; h < 4; ++h) {
            int c0 = cg * 8 + h * 2;
            const float* s0 = (c0 < 32) ? old_ : new_;
            const float* s1 = ((c0 + 1) < 32) ? old_ : new_;
            float f0 = s0[((size_t)b * 32 + (c0 & 31)) * PLANE + pixbase + tid];
            float f1 = s1[((size_t)b * 32 + ((c0 + 1) & 31)) * PLANE + pixbase + tid];
            pk[h] = pack2h(f0, f1);
        }
        int p16 = cg ^ (tid & 7);
        uint4 v; v.x = pk[0]; v.y = pk[1]; v.z = pk[2]; v.w = pk[3];
        *reinterpret_cast<uint4*>(&lds[tid * 64 + p16 * 8]) = v;
    }
    __syncthreads();
    for (int r = 0; r < 8; ++r) {
        int u = r * 256 + tid;
        int pix = u >> 3, p16 = u & 7;
        uint4 v = *reinterpret_cast<const uint4*>(&lds[pix * 64 + ((p16 ^ (pix & 7)) * 8)]);
        *reinterpret_cast<uint4*>(
            &xb[((size_t)b * PLANE + pixbase + pix) * 64 + p16 * 8]) = v;
    }
}

// ---------------- weight prep: fp32 OIHW -> fp16 [9][64][CIN] ----------------
__global__ void prep_wstd(const float* __restrict__ wq, const float* __restrict__ wk,
                          const float* __restrict__ wo1, const float* __restrict__ wo2,
                          const float* __restrict__ rw1, const float* __restrict__ rw2,
                          unsigned short* __restrict__ wstd)
{
    const int c = blockIdx.y;  // 0..19
    const float* src;
    if (c == 0) src = wq;
    else if (c == 1) src = wk;
    else if (c == 2) src = wo1;
    else if (c == 3) src = wo2;
    else if (c < 12) src = rw1 + (size_t)(c - 4) * 36864;
    else src = rw2 + (size_t)(c - 12) * 36864;
    int idx = blockIdx.x * 256 + threadIdx.x;  // 0..4095
    int o = idx >> 6, i = idx & 63;
    const float* s = src + (size_t)(o * 64 + i) * 9;
    unsigned short* d = wstd + (size_t)c * 36864 + (size_t)o * 64 + i;
#pragma unroll
    for (int t = 0; t < 9; ++t) d[(size_t)t * 4096] = f2h(s[t]);
}

__global__ void prep_wv(const float* __restrict__ wv, unsigned short* __restrict__ wv96)
{
    int idx = blockIdx.x * 256 + threadIdx.x;  // < 6144
    int o = idx / 96, i = idx - o * 96;
    unsigned short* d = wv96 + (size_t)o * 96 + i;
    if (i < 81) {
        const float* s = wv + (size_t)(o * 81 + i) * 9;
#pragma unroll
        for (int t = 0; t < 9; ++t) d[(size_t)t * 6144] = f2h(s[t]);
    } else {
#pragma unroll
        for (int t = 0; t < 9; ++t) d[(size_t)t * 6144] = 0;
    }
}

extern "C" void kernel_launch(void* const* d_in, const int* in_sizes, int n_in,
                              void* d_out, int out_size, void* d_ws, size_t ws_size,
                              hipStream_t stream)
{
    const float* old_ = (const float*)d_in[0];
    const float* new_ = (const float*)d_in[1];
    const float* wq  = (const float*)d_in[2];  const float* bq  = (const float*)d_in[3];
    const float* wk  = (const float*)d_in[4];  const float* bk  = (const float*)d_in[5];
    const float* wv  = (const float*)d_in[6];  const float* bv  = (const float*)d_in[7];
    const float* wo1 = (const float*)d_in[8];  const float* bo1 = (const float*)d_in[9];
    const float* rw1 = (const float*)d_in[10]; const float* rw2 = (const float*)d_in[11];
    const float* wo2 = (const float*)d_in[12]; const float* bo2 = (const float*)d_in[13];
    float* out = (float*)d_out;

    char* ws = (char*)d_ws;
    // X : xh fp16 (32 MiB, persistent)
    // P1: q -> y_a (32 MiB) ; P2: k -> xv -> h1 (32 MiB) ; P3: att96(48) -> y_b
    unsigned short* X   = (unsigned short*)(ws);
    unsigned short* P1  = (unsigned short*)(ws + 33554432ull);
    unsigned short* P2  = (unsigned short*)(ws + 67108864ull);
    unsigned short* P3  = (unsigned short*)(ws + 100663296ull);
    unsigned short* wst = (unsigned short*)(ws + 150994944ull);   // 20*36864 fp16
    unsigned short* wv96= (unsigned short*)(ws + 152469504ull);   // 9*64*96 fp16

    const dim3 cgrid(16, 16, 4), cblk(256);

    prep_wstd<<<dim3(16, 20), 256, 0, stream>>>(wq, wk, wo1, wo2, rw1, rw2, wst);
    prep_wv<<<dim3(24), 256, 0, stream>>>(wv, wv96);
    pack_x<<<dim3(256, 4), 256, 0, stream>>>(old_, new_, X);

    // q = conv(x, wq, bq); k = conv(x, wk, bk)
    conv_mfma<64, true, false, false, false, false, false, true>
        <<<cgrid, cblk, 0, stream>>>(X, wst + 0ull * 36864, bq, nullptr, nullptr, nullptr, P1);
    conv_mfma<64, true, false, false, false, false, false, true>
        <<<cgrid, cblk, 0, stream>>>(X, wst + 1ull * 36864, bk, nullptr, nullptr, nullptr, P2);
    // att (fp16, 96ch padded)
    local_sim<<<cgrid, dim3(128), 0, stream>>>(P1, P2, P3);
    // xv = x * (conv(att, wv) + bv)   [MULX fused]
    conv_mfma<96, true, false, false, false, true, false, true>
        <<<cgrid, cblk, 0, stream>>>(P3, wv96, bv, nullptr, X, nullptr, P2);
    // y0 = conv(xv, wo1, bo1) -> P1
    conv_mfma<64, true, false, false, false, false, false, true>
        <<<cgrid, cblk, 0, stream>>>(P2, wst + 2ull * 36864, bo1, nullptr, nullptr, nullptr, P1);
    // 8 ResBlocks; y ping-pong P1 <-> P3, h1 in P2; residual add fused in conv2
    for (int i = 0; i < 8; ++i) {
        unsigned short* ysrc = (i & 1) ? P3 : P1;
        unsigned short* ydst = (i & 1) ? P1 : P3;
        conv_mfma<64, false, true, false, false, false, false, true>
            <<<cgrid, cblk, 0, stream>>>(ysrc, wst + (size_t)(4 + i) * 36864, nullptr,
                                         nullptr, nullptr, nullptr, P2);
        conv_mfma<64, false, false, true, false, false, false, true>
            <<<cgrid, cblk, 0, stream>>>(P2, wst + (size_t)(12 + i) * 36864, nullptr,
                                         ysrc, nullptr, nullptr, ydst);
    }
    // out = conv(y, wo2, bo2) + x   [ADDX fused]; final y in P1
    conv_mfma<64, true, false, false, true, false, true, false>
        <<<cgrid, cblk, 0, stream>>>(P1, wst + 3ull * 36864, bo2, nullptr, X, out, nullptr);
}

// Round 7
// 833.325 us; speedup vs baseline: 1.7915x; 1.0709x over previous
//
#include <hip/hip_runtime.h>
#include <hip/hip_bf16.h>

// SRPBlock forward — fp16 end-to-end MFMA implicit-GEMM convs + LDS-tiled local attention.
// x=concat(old,new) [4,64,256,256] fp32 NCHW inputs; all activations flow as fp16
// [b][pix][ch] (channel-contiguous); fp32 accumulate everywhere; final out fp32 NCHW.
//
// This revision:
//  * local_sim: reverted to the round-2 version (256 thr, 1 px/thread, 70 us).
//    R6 proved it's TLP-bound, not LDS-BW-bound (2px/thread cut traffic 44% but
//    halved waves -> 84 us).
//  * conv_mfma: SAME tile (16x16), grid (16,16,4), LDS layouts, swizzles, fragment
//    reads, MFMA order as round 2. Only the SCHEDULE changes: input halo is
//    double-buffered (in0|in1|w = 76.5 KB, still 2 blocks/CU); next chunk's input
//    staged asynchronously BEFORE computing the current chunk, so its L2/L3 drain
//    hides under the 144 MFMAs. Weights re-staged per chunk (L2-hot 36 KB).

#define HH 256
#define WW 256
#define PLANE 65536

typedef _Float16 f16x8 __attribute__((ext_vector_type(8)));
typedef float    f32x4 __attribute__((ext_vector_type(4)));
typedef _Float16 h2    __attribute__((ext_vector_type(2)));

__device__ __forceinline__ unsigned short f2h(float f) {
    _Float16 h = (_Float16)f;                  // v_cvt_f16_f32 (RNE)
    return __builtin_bit_cast(unsigned short, h);
}
__device__ __forceinline__ float h2f(unsigned short u) {
    return (float)__builtin_bit_cast(_Float16, u);
}
__device__ __forceinline__ unsigned pack2h(float a, float b) {
    return (unsigned)f2h(a) | ((unsigned)f2h(b) << 16);
}
__device__ __forceinline__ float dot2h(unsigned a, unsigned b, float c) {
#if __has_builtin(__builtin_amdgcn_fdot2)
    return __builtin_amdgcn_fdot2(__builtin_bit_cast(h2, a),
                                  __builtin_bit_cast(h2, b), c, false);
#else
    h2 av = __builtin_bit_cast(h2, a), bv = __builtin_bit_cast(h2, b);
    return fmaf((float)av.x, (float)bv.x, fmaf((float)av.y, (float)bv.y, c));
#endif
}

// async 16B global -> LDS. LDS dest is wave-uniform base + lane*16 (linear);
// per-lane swizzling must be applied to the GLOBAL source address.
__device__ __forceinline__ void gl16(const unsigned short* g, unsigned short* l) {
    __builtin_amdgcn_global_load_lds(
        (const __attribute__((address_space(1))) unsigned int*)(g),
        (__attribute__((address_space(3))) unsigned int*)(l),
        16, 0, 0);
}

// ---------------- conv3x3 (pad=1, Cout=64) via MFMA 16x16x32 f16 ----------------
// block = 256 thr = 4 waves; tile = 16x16 pixels x 64 outch.
// K = 9 taps x CIN, chunked by 32 channels; ALL 9 taps' weights staged per chunk.
// Input halo double-buffered: stage(c+1) issued before compute(c) -> drain hidden.
// LDS: in0 (20.25 KB) + in1 (20.25 KB) + w 9*64*32 (36 KB) = 76.5 KB, 2 blocks/CU;
// union'd with the 32 KB epilogue transpose region.
template <int CIN, bool BIAS, bool LEAKY, bool ADDF, bool ADDX, bool MULX, bool OUTF, bool OUTB>
__global__ __launch_bounds__(256, 2) void conv_mfma(
    const unsigned short* __restrict__ in_pc,  // [b][65536][CIN] fp16
    const unsigned short* __restrict__ wb,     // [9][64][CIN] fp16
    const float* __restrict__ bias,
    const unsigned short* __restrict__ addh,   // fp16 [b][pix][64] addend (residual)
    const unsigned short* __restrict__ xh,     // fp16 [b][pix][64] (concat x)
    float* __restrict__ outf,                  // fp32 NCHW
    unsigned short* __restrict__ outb)         // fp16 [b][65536][64]
{
    __shared__ unsigned short smem[39168];     // 76.5 KB: in0 | in1 | w
    unsigned short* lds_w = smem + 20736;      // 9*64*32 = 18432 halves

    const int tid = threadIdx.x;
    const int w   = tid >> 6;
    const int ln  = tid & 63;
    const int m   = ln & 15;    // outch-in-group for A; pixel-col for B/D
    const int q   = ln >> 4;    // quad
    const int b   = blockIdx.z;
    const int tx0 = blockIdx.x * 16, ty0 = blockIdx.y * 16;
    const size_t pixb = (size_t)b * PLANE;
    const bool interior = (blockIdx.x >= 1) && (blockIdx.x <= 14) &&
                          (blockIdx.y >= 1) && (blockIdx.y <= 14);

    // stage input halo chunk c2s (324 px x 32 ch) into dst (same layout as R2)
    auto stage_in = [&](int c2s, unsigned short* dst) {
        if (interior) {
            // unchecked async path: linear LDS dest, swizzled global source
            const unsigned short* inb =
                in_pc + (pixb + (size_t)(ty0 - 1) * 256 + (tx0 - 1)) * CIN + c2s * 32;
#pragma unroll
            for (int it = 0; it < 5; ++it) {
                int u = it * 256 + tid;
                int pix = u >> 2, ps = u & 3;
                int part = ps ^ (pix & 3);
                int hy = pix / 18, hx = pix - hy * 18;
                gl16(inb + ((size_t)hy * 256 + hx) * CIN + part * 8,
                     &dst[(it * 256 + (tid & 192)) * 8]);
            }
            if (tid < 16) {   // tail: u = 1280..1295 (wave 0, lanes 0..15)
                int u = 1280 + tid;
                int pix = u >> 2, ps = u & 3;
                int part = ps ^ (pix & 3);
                int hy = pix / 18, hx = pix - hy * 18;
                gl16(inb + ((size_t)hy * 256 + hx) * CIN + part * 8,
                     &dst[1280 * 8]);
            }
        } else {
            // boundary path: checked, zero-filled, via VGPRs
            for (int u = tid; u < 1296; u += 256) {
                int pix = u >> 2, part = u & 3;
                int hy = pix / 18, hx = pix - hy * 18;
                int gy = ty0 + hy - 1, gx = tx0 + hx - 1;
                uint4 val = make_uint4(0u, 0u, 0u, 0u);
                if ((unsigned)gy < 256u && (unsigned)gx < 256u)
                    val = *reinterpret_cast<const uint4*>(
                        in_pc + ((pixb + (size_t)gy * 256 + gx) * CIN + c2s * 32 + part * 8));
                *reinterpret_cast<uint4*>(&dst[pix * 32 + ((part ^ (pix & 3)) * 8)]) = val;
            }
        }
    };
    // stage all 9 taps' weights for chunk c2s: 9 x 64 oc x 32 ch (async)
    auto stage_w = [&](int c2s) {
        const int oc = tid >> 2, ps = tid & 3;
        const int part = ps ^ (oc & 3);
        const unsigned short* wsrc = wb + (size_t)oc * CIN + c2s * 32 + part * 8;
#pragma unroll
        for (int t = 0; t < 9; ++t)
            gl16(wsrc + (size_t)t * 64 * CIN,
                 &lds_w[t * 2048 + (tid & 192) * 8]);
    };

    f32x4 acc[4][4];
#pragma unroll
    for (int g = 0; g < 4; ++g)
#pragma unroll
        for (int p = 0; p < 4; ++p) acc[g][p] = (f32x4)0.f;

    constexpr int NC = CIN / 32;

    // prologue: chunk-0 input + weights; single drain
    stage_in(0, smem);
    stage_w(0);
    __syncthreads();

    for (int c2 = 0; c2 < NC; ++c2) {
        unsigned short* cbuf = (c2 & 1) ? smem + 10368 : smem;
        if (c2 + 1 < NC)   // async prefetch of next input chunk (hidden under MFMAs)
            stage_in(c2 + 1, ((c2 + 1) & 1) ? smem + 10368 : smem);

#pragma unroll
        for (int t = 0; t < 9; ++t) {
            const int dy = t / 3, dx = t - dy * 3;
            f16x8 av[4], bv[4];
#pragma unroll
            for (int g = 0; g < 4; ++g) {
                int oc = g * 16 + m;
                av[g] = *reinterpret_cast<const f16x8*>(
                    &lds_w[t * 2048 + oc * 32 + ((q ^ (oc & 3)) * 8)]);
            }
#pragma unroll
            for (int p = 0; p < 4; ++p) {
                int hp = (w * 4 + p + dy) * 18 + m + dx;
                bv[p] = *reinterpret_cast<const f16x8*>(
                    &cbuf[hp * 32 + ((q ^ (hp & 3)) * 8)]);
            }
#pragma unroll
            for (int g = 0; g < 4; ++g)
#pragma unroll
                for (int p = 0; p < 4; ++p)
                    acc[g][p] = __builtin_amdgcn_mfma_f32_16x16x32_f16(
                        av[g], bv[p], acc[g][p], 0, 0, 0);
        }

        if (c2 + 1 < NC) {
            __syncthreads();        // end w(c2) reads; drains prefetched input too
            stage_w(c2 + 1);        // L2-hot 36 KB
            __syncthreads();        // drain weights
        }
    }

    // ---------------- epilogue ----------------
    // D layout: row(outch-in-grp) = q*4+reg, col(pixel) = m
    const int colx = tx0 + m;
    float4 bvec[4];
    if (BIAS) {
#pragma unroll
        for (int g = 0; g < 4; ++g)
            bvec[g] = *reinterpret_cast<const float4*>(bias + g * 16 + q * 4);
    }
    if (OUTB) __syncthreads();   // protect last chunk's LDS reads before overwrite

#pragma unroll
    for (int g = 0; g < 4; ++g) {
#pragma unroll
        for (int p = 0; p < 4; ++p) {
            const int prow = w * 4 + p;
            const int gy   = ty0 + prow;
            const size_t pixg = pixb + (size_t)gy * 256 + colx;
            const int oc0 = g * 16 + q * 4;
            ushort4 a4, x4;
            if (ADDF) a4 = *reinterpret_cast<const ushort4*>(addh + pixg * 64 + oc0);
            if (ADDX || MULX) x4 = *reinterpret_cast<const ushort4*>(xh + pixg * 64 + oc0);
            float vals[4];
#pragma unroll
            for (int r = 0; r < 4; ++r) {
                float v = acc[g][p][r];
                if (BIAS) v += reinterpret_cast<const float*>(&bvec[g])[r];
                if (LEAKY) v = (v >= 0.f) ? v : 0.2f * v;
                if (ADDF) v += h2f(reinterpret_cast<const unsigned short*>(&a4)[r]);
                if (ADDX) v += h2f(reinterpret_cast<const unsigned short*>(&x4)[r]);
                if (MULX) v *= h2f(reinterpret_cast<const unsigned short*>(&x4)[r]);
                if (OUTF)
                    outf[((size_t)(b * 64 + oc0 + r)) * PLANE + (size_t)gy * 256 + colx] = v;
                vals[r] = v;
            }
            if (OUTB) {  // stage to LDS for [pix][64] vector store
                ushort4 pk;
                pk.x = f2h(vals[0]); pk.y = f2h(vals[1]);
                pk.z = f2h(vals[2]); pk.w = f2h(vals[3]);
                int pix   = prow * 16 + m;
                int part8 = g * 4 + q;
                int p16   = (part8 >> 1) ^ (pix & 7);
                *reinterpret_cast<ushort4*>(&smem[pix * 64 + p16 * 8 + (part8 & 1) * 4]) = pk;
            }
        }
    }
    if (OUTB) {
        __syncthreads();
        for (int u = tid; u < 2048; u += 256) {
            int pix = u >> 3, p16 = u & 7;
            uint4 val = *reinterpret_cast<const uint4*>(
                &smem[pix * 64 + ((p16 ^ (pix & 7)) * 8)]);
            int gy = ty0 + (pix >> 4), gx = tx0 + (pix & 15);
            *reinterpret_cast<uint4*>(
                &outb[(pixb + (size_t)gy * 256 + gx) * 64 + p16 * 8]) = val;
        }
    }
}

// ---------------- local similarity (LDS-tiled, fp16 dot2, di-grouped) ----------------
// att[b][pix][p] = dot64(q[pix], k[pix+(di-4,dj-4)]), p=di*9+dj; ch 81..95 = 0.
// Full 64-ch 24x24 K halo staged ONCE (72 KB LDS); g-outer loop keeps only acc[27]
// live (no spills). Round-2 version verbatim (70 us verified).
__global__ __launch_bounds__(256)
void local_sim(
    const unsigned short* __restrict__ qh, const unsigned short* __restrict__ kh,
    unsigned short* __restrict__ att)
{
    __shared__ unsigned short lds_k[576 * 64];   // 24*24 px x 64ch fp16 = 73.7 KB

    const int tid = threadIdx.x;
    const int tx = tid & 15, ty = tid >> 4;
    const int bx = blockIdx.x * 16, by = blockIdx.y * 16;
    const int b  = blockIdx.z;
    const size_t pixb = (size_t)b * PLANE;
    const bool interior = (blockIdx.x >= 1) && (blockIdx.x <= 14) &&
                          (blockIdx.y >= 1) && (blockIdx.y <= 14);

    // ---- stage K halo 24x24 x 64ch once; slot = part ^ ((pix ^ pix>>3) & 7) ----
    if (interior) {
        const unsigned short* kb =
            kh + (pixb + (size_t)(by - 4) * 256 + (bx - 4)) * 64;
#pragma unroll
        for (int it = 0; it < 18; ++it) {
            int u = it * 256 + tid;
            int pix = u >> 3, sl = u & 7;
            int part = sl ^ ((pix ^ (pix >> 3)) & 7);
            int hy = pix / 24, hx = pix - hy * 24;
            gl16(kb + ((size_t)hy * 256 + hx) * 64 + part * 8,
                 &lds_k[(it * 256 + (tid & 192)) * 8]);
        }
    } else {
        for (int u = tid; u < 4608; u += 256) {
            int pix = u >> 3, part = u & 7;
            int hy = pix / 24, hx = pix - hy * 24;
            int gy = by + hy - 4, gx = bx + hx - 4;
            uint4 val = make_uint4(0u, 0u, 0u, 0u);
            if ((unsigned)gy < 256u && (unsigned)gx < 256u)
                val = *reinterpret_cast<const uint4*>(
                    kh + ((pixb + (size_t)gy * 256 + gx) * 64 + part * 8));
            int sl = part ^ ((pix ^ (pix >> 3)) & 7);
            *reinterpret_cast<uint4*>(&lds_k[pix * 64 + sl * 8]) = val;
        }
    }
    __syncthreads();

    const unsigned short* qbase = qh + (pixb + (size_t)(by + ty) * 256 + bx + tx) * 64;
    unsigned short* op = att + (pixb + (size_t)(by + ty) * 256 + bx + tx) * 96;

    uint4 qv[8];
#pragma unroll
    for (int j = 0; j < 8; ++j)
        qv[j] = *reinterpret_cast<const uint4*>(qbase + j * 8);

#pragma unroll
    for (int g = 0; g < 3; ++g) {
        float acc[27];
#pragma unroll
        for (int i = 0; i < 27; ++i) acc[i] = 0.f;

#pragma unroll
        for (int dil = 0; dil < 3; ++dil) {
            const int hrow = (ty + g * 3 + dil) * 24 + tx;
#pragma unroll
            for (int dj = 0; dj < 9; ++dj) {
                const int hp = hrow + dj;
                const int gs = (hp ^ (hp >> 3)) & 7;
                float s = acc[dil * 9 + dj];
#pragma unroll
                for (int part = 0; part < 8; ++part) {
                    const uint4 kv = *reinterpret_cast<const uint4*>(
                        &lds_k[hp * 64 + ((part ^ gs) * 8)]);
                    s = dot2h(qv[part].x, kv.x, s);
                    s = dot2h(qv[part].y, kv.y, s);
                    s = dot2h(qv[part].z, kv.z, s);
                    s = dot2h(qv[part].w, kv.w, s);
                }
                acc[dil * 9 + dj] = s;
            }
        }

        // ---- store this group's 27 fp16 values at op + g*27 ----
        unsigned short* o = op + g * 27;
        if (g == 0) {
            uint4 A = {pack2h(acc[0], acc[1]),  pack2h(acc[2], acc[3]),
                       pack2h(acc[4], acc[5]),  pack2h(acc[6], acc[7])};
            uint4 B = {pack2h(acc[8], acc[9]),  pack2h(acc[10], acc[11]),
                       pack2h(acc[12], acc[13]), pack2h(acc[14], acc[15])};
            uint2 C = {pack2h(acc[16], acc[17]), pack2h(acc[18], acc[19])};
            uint2 D = {pack2h(acc[20], acc[21]), pack2h(acc[22], acc[23])};
            *reinterpret_cast<uint4*>(o)      = A;
            *reinterpret_cast<uint4*>(o + 8)  = B;
            *reinterpret_cast<uint2*>(o + 16) = C;
            *reinterpret_cast<uint2*>(o + 20) = D;
            *reinterpret_cast<unsigned*>(o + 24) = pack2h(acc[24], acc[25]);
            o[26] = f2h(acc[26]);
        } else if (g == 1) {
            o[0] = f2h(acc[0]);
            *reinterpret_cast<unsigned*>(o + 1) = pack2h(acc[1], acc[2]);
            *reinterpret_cast<unsigned*>(o + 3) = pack2h(acc[3], acc[4]);
            uint4 A = {pack2h(acc[5], acc[6]),   pack2h(acc[7], acc[8]),
                       pack2h(acc[9], acc[10]),  pack2h(acc[11], acc[12])};
            uint4 B = {pack2h(acc[13], acc[14]), pack2h(acc[15], acc[16]),
                       pack2h(acc[17], acc[18]), pack2h(acc[19], acc[20])};
            *reinterpret_cast<uint4*>(o + 5)  = A;
            *reinterpret_cast<uint4*>(o + 13) = B;
            uint2 C = {pack2h(acc[21], acc[22]), pack2h(acc[23], acc[24])};
            *reinterpret_cast<uint2*>(o + 21) = C;
            *reinterpret_cast<unsigned*>(o + 25) = pack2h(acc[25], acc[26]);
        } else {
            *reinterpret_cast<unsigned*>(o) = pack2h(acc[0], acc[1]);
            uint4 A = {pack2h(acc[2], acc[3]),   pack2h(acc[4], acc[5]),
                       pack2h(acc[6], acc[7]),   pack2h(acc[8], acc[9])};
            uint4 B = {pack2h(acc[10], acc[11]), pack2h(acc[12], acc[13]),
                       pack2h(acc[14], acc[15]), pack2h(acc[16], acc[17])};
            *reinterpret_cast<uint4*>(o + 2)  = A;
            *reinterpret_cast<uint4*>(o + 10) = B;
            uint2 C = {pack2h(acc[18], acc[19]), pack2h(acc[20], acc[21])};
            *reinterpret_cast<uint2*>(o + 18) = C;
            *reinterpret_cast<unsigned*>(o + 22) = pack2h(acc[22], acc[23]);
            *reinterpret_cast<unsigned*>(o + 24) = pack2h(acc[24], acc[25]);
            o[26] = f2h(acc[26]);
        }
    }

    // zero channels 81..95
    op[81] = 0;
    *reinterpret_cast<unsigned*>(op + 82) = 0u;
    uint2 z2 = {0u, 0u};
    uint4 z4 = {0u, 0u, 0u, 0u};
    *reinterpret_cast<uint2*>(op + 84) = z2;
    *reinterpret_cast<uint4*>(op + 88) = z4;
}

// ---------------- pack x: fp32 NCHW old/new -> fp16 [b][pix][64] ----------------
__global__ __launch_bounds__(256) void pack_x(
    const float* __restrict__ old_, const float* __restrict__ new_,
    unsigned short* __restrict__ xb)
{
    __shared__ unsigned short lds[256 * 64];
    const int tid = threadIdx.x;
    const int b = blockIdx.y;
    const size_t pixbase = (size_t)blockIdx.x * 256;
#pragma unroll
    for (int cg = 0; cg < 8; ++cg) {
        unsigned pk[4];
#pragma unroll
        for (int h = 0; h < 4; ++h) {
            int c0 = cg * 8 + h * 2;
            const float* s0 = (c0 < 32) ? old_ : new_;
            const float* s1 = ((c0 + 1) < 32) ? old_ : new_;
            float f0 = s0[((size_t)b * 32 + (c0 & 31)) * PLANE + pixbase + tid];
            float f1 = s1[((size_t)b * 32 + ((c0 + 1) & 31)) * PLANE + pixbase + tid];
            pk[h] = pack2h(f0, f1);
        }
        int p16 = cg ^ (tid & 7);
        uint4 v; v.x = pk[0]; v.y = pk[1]; v.z = pk[2]; v.w = pk[3];
        *reinterpret_cast<uint4*>(&lds[tid * 64 + p16 * 8]) = v;
    }
    __syncthreads();
    for (int r = 0; r < 8; ++r) {
        int u = r * 256 + tid;
        int pix = u >> 3, p16 = u & 7;
        uint4 v = *reinterpret_cast<const uint4*>(&lds[pix * 64 + ((p16 ^ (pix & 7)) * 8)]);
        *reinterpret_cast<uint4*>(
            &xb[((size_t)b * PLANE + pixbase + pix) * 64 + p16 * 8]) = v;
    }
}

// ---------------- weight prep: fp32 OIHW -> fp16 [9][64][CIN] ----------------
__global__ void prep_wstd(const float* __restrict__ wq, const float* __restrict__ wk,
                          const float* __restrict__ wo1, const float* __restrict__ wo2,
                          const float* __restrict__ rw1, const float* __restrict__ rw2,
                          unsigned short* __restrict__ wstd)
{
    const int c = blockIdx.y;  // 0..19
    const float* src;
    if (c == 0) src = wq;
    else if (c == 1) src = wk;
    else if (c == 2) src = wo1;
    else if (c == 3) src = wo2;
    else if (c < 12) src = rw1 + (size_t)(c - 4) * 36864;
    else src = rw2 + (size_t)(c - 12) * 36864;
    int idx = blockIdx.x * 256 + threadIdx.x;  // 0..4095
    int o = idx >> 6, i = idx & 63;
    const float* s = src + (size_t)(o * 64 + i) * 9;
    unsigned short* d = wstd + (size_t)c * 36864 + (size_t)o * 64 + i;
#pragma unroll
    for (int t = 0; t < 9; ++t) d[(size_t)t * 4096] = f2h(s[t]);
}

__global__ void prep_wv(const float* __restrict__ wv, unsigned short* __restrict__ wv96)
{
    int idx = blockIdx.x * 256 + threadIdx.x;  // < 6144
    int o = idx / 96, i = idx - o * 96;
    unsigned short* d = wv96 + (size_t)o * 96 + i;
    if (i < 81) {
        const float* s = wv + (size_t)(o * 81 + i) * 9;
#pragma unroll
        for (int t = 0; t < 9; ++t) d[(size_t)t * 6144] = f2h(s[t]);
    } else {
#pragma unroll
        for (int t = 0; t < 9; ++t) d[(size_t)t * 6144] = 0;
    }
}

extern "C" void kernel_launch(void* const* d_in, const int* in_sizes, int n_in,
                              void* d_out, int out_size, void* d_ws, size_t ws_size,
                              hipStream_t stream)
{
    const float* old_ = (const float*)d_in[0];
    const float* new_ = (const float*)d_in[1];
    const float* wq  = (const float*)d_in[2];  const float* bq  = (const float*)d_in[3];
    const float* wk  = (const float*)d_in[4];  const float* bk  = (const float*)d_in[5];
    const float* wv  = (const float*)d_in[6];  const float* bv  = (const float*)d_in[7];
    const float* wo1 = (const float*)d_in[8];  const float* bo1 = (const float*)d_in[9];
    const float* rw1 = (const float*)d_in[10]; const float* rw2 = (const float*)d_in[11];
    const float* wo2 = (const float*)d_in[12]; const float* bo2 = (const float*)d_in[13];
    float* out = (float*)d_out;

    char* ws = (char*)d_ws;
    // X : xh fp16 (32 MiB, persistent)
    // P1: q -> y_a (32 MiB) ; P2: k -> xv -> h1 (32 MiB) ; P3: att96(48) -> y_b
    unsigned short* X   = (unsigned short*)(ws);
    unsigned short* P1  = (unsigned short*)(ws + 33554432ull);
    unsigned short* P2  = (unsigned short*)(ws + 67108864ull);
    unsigned short* P3  = (unsigned short*)(ws + 100663296ull);
    unsigned short* wst = (unsigned short*)(ws + 150994944ull);   // 20*36864 fp16
    unsigned short* wv96= (unsigned short*)(ws + 152469504ull);   // 9*64*96 fp16

    const dim3 cgrid(16, 16, 4), cblk(256);

    prep_wstd<<<dim3(16, 20), 256, 0, stream>>>(wq, wk, wo1, wo2, rw1, rw2, wst);
    prep_wv<<<dim3(24), 256, 0, stream>>>(wv, wv96);
    pack_x<<<dim3(256, 4), 256, 0, stream>>>(old_, new_, X);

    // q = conv(x, wq, bq); k = conv(x, wk, bk)
    conv_mfma<64, true, false, false, false, false, false, true>
        <<<cgrid, cblk, 0, stream>>>(X, wst + 0ull * 36864, bq, nullptr, nullptr, nullptr, P1);
    conv_mfma<64, true, false, false, false, false, false, true>
        <<<cgrid, cblk, 0, stream>>>(X, wst + 1ull * 36864, bk, nullptr, nullptr, nullptr, P2);
    // att (fp16, 96ch padded)
    local_sim<<<cgrid, cblk, 0, stream>>>(P1, P2, P3);
    // xv = x * (conv(att, wv) + bv)   [MULX fused]
    conv_mfma<96, true, false, false, false, true, false, true>
        <<<cgrid, cblk, 0, stream>>>(P3, wv96, bv, nullptr, X, nullptr, P2);
    // y0 = conv(xv, wo1, bo1) -> P1
    conv_mfma<64, true, false, false, false, false, false, true>
        <<<cgrid, cblk, 0, stream>>>(P2, wst + 2ull * 36864, bo1, nullptr, nullptr, nullptr, P1);
    // 8 ResBlocks; y ping-pong P1 <-> P3, h1 in P2; residual add fused in conv2
    for (int i = 0; i < 8; ++i) {
        unsigned short* ysrc = (i & 1) ? P3 : P1;
        unsigned short* ydst = (i & 1) ? P1 : P3;
        conv_mfma<64, false, true, false, false, false, false, true>
            <<<cgrid, cblk, 0, stream>>>(ysrc, wst + (size_t)(4 + i) * 36864, nullptr,
                                         nullptr, nullptr, nullptr, P2);
        conv_mfma<64, false, false, true, false, false, false, true>
            <<<cgrid, cblk, 0, stream>>>(P2, wst + (size_t)(12 + i) * 36864, nullptr,
                                         ysrc, nullptr, nullptr, ydst);
    }
    // out = conv(y, wo2, bo2) + x   [ADDX fused]; final y in P1
    conv_mfma<64, true, false, false, true, false, true, false>
        <<<cgrid, cblk, 0, stream>>>(P1, wst + 3ull * 36864, bo2, nullptr, X, out, nullptr);
}